// Round 6
// baseline (2988.677 us; speedup 1.0000x reference)
//
#include <hip/hip_runtime.h>
#include <cstdint>
#include <cstddef>

// Problem constants
#define NB    64      // batch
#define NS    4096    // seq len
#define NH    1024    // hidden
#define NOPSN 8
#define NSTEP 10

#define GRID  256
#define TPB   1024    // 16 waves/block, 1 block/CU -> 4 waves/SIMD

// Workspace layout (float offsets), ~5.5 MB (same as R5).
#define OFF_HN   0u          // hn  [64][1024]
#define OFF_HNT  65536u      // hnT [512][128] (k-pair interleave)
#define OFF_H    131072u     // h   [64][1024]
#define OFF_CAND 196608u     // cand [64][256] float2 (val, idx)
#define OFF_OPP  229376u     // opp [10][16 jg][64 b][8 o]
#define OFF_PC   311296u     // pc  [16 kg][16 jg][64 b][64 j]  (4 MB)
#define OFF_CTRL 1359872u    // ints: [0]=magic [1]=barrier cnt [2..11]=stopcnt[t]
#define MAGIC    0x1357A5E5

typedef float f2v  __attribute__((ext_vector_type(2)));
typedef float f4v  __attribute__((ext_vector_type(4)));
typedef float f16v __attribute__((ext_vector_type(16)));

__device__ __forceinline__ float bcastf(float v, int l) {
  return __int_as_float(__builtin_amdgcn_readlane(__float_as_int(v), l));
}

// Device-scope grid barrier with full fences (R3-verified).
__device__ __forceinline__ void gridbar(int* cnt, int target) {
  __syncthreads();
  if (threadIdx.x == 0) {
    __threadfence();  // release (device scope)
    __hip_atomic_fetch_add(cnt, 1, __ATOMIC_RELAXED, __HIP_MEMORY_SCOPE_AGENT);
    while (__hip_atomic_load(cnt, __ATOMIC_RELAXED, __HIP_MEMORY_SCOPE_AGENT) < target)
      __builtin_amdgcn_s_sleep(1);
    __threadfence();  // acquire
  }
  __syncthreads();
}

__global__ void __launch_bounds__(TPB, 4)
sys1_kernel(const float* __restrict__ s2a,  const float* __restrict__ Wres,
            const float* __restrict__ bres, const float* __restrict__ Wop,
            const float* __restrict__ bop,  const float* __restrict__ Wx,
            const float* __restrict__ bx,   const float* __restrict__ noise,
            float* __restrict__ out,        float* __restrict__ wsf)
{
  // 112.5 KB static LDS (gfx950: 160 KiB/CU, 1 block/CU):
  // [0,16384)        WxL  [1024 k][16 s]   (persistent, staged once)
  // [16384,24576)    WresL[128 k][64 j]    (persistent, staged once)
  // [24576,28672)    scratch (A: 1024 fl atomics; C: 4096 fl; D: 1024 fl)
  // [28672,28736)    ptrSm (64 ints)
  __shared__ float smem[28800];
  float* __restrict__ WxL   = smem;
  float* __restrict__ WresL = smem + 16384;
  float* __restrict__ smA   = smem + 24576;
  int*   __restrict__ ptrSm = (int*)(smem + 28672);

  float* __restrict__ hn  = wsf + OFF_HN;
  float* __restrict__ hnT = wsf + OFF_HNT;
  float* __restrict__ h   = wsf + OFF_H;
  float* __restrict__ opp = wsf + OFF_OPP;
  float* __restrict__ pc  = wsf + OFF_PC;
  int* ctrl = (int*)(wsf + OFF_CTRL);
  int* cnt  = ctrl + 1;

  const int tid = threadIdx.x;
  const int blk = blockIdx.x;

  // ---- bootstrap: block 0 inits ctrl (ws is poisoned every launch) ----
  if (blk == 0 && tid == 0) {
    #pragma unroll
    for (int i = 1; i < 32; ++i) ctrl[i] = 0;
    __threadfence();
    __hip_atomic_store(&ctrl[0], (int)MAGIC, __ATOMIC_RELEASE, __HIP_MEMORY_SCOPE_AGENT);
  }
  if (tid == 0) {
    while (__hip_atomic_load(&ctrl[0], __ATOMIC_RELAXED, __HIP_MEMORY_SCOPE_AGENT) != (int)MAGIC)
      __builtin_amdgcn_s_sleep(1);
  }
  __syncthreads();

  const int lane = tid & 63;
  const int wv   = __builtin_amdgcn_readfirstlane(tid >> 6);   // wave 0..15

  const int s0A = blk << 4;            // phase-A s-cols
  const int kbaseA = wv << 6;          // phase-A wave k-slice
  const int jgC = blk & 15, kgC = blk >> 4;
  const int j0C = jgC << 6, k0C = kgC << 7;

  // ---- stage persistent weights into LDS (once; immune to fences/remat) ----
  {
    // WxL: thread t stages row k=t: Wx[t][s0A..s0A+15]
    const float* src = Wx + (size_t)tid * NS + s0A;
    f4v* dst = (f4v*)(WxL + tid * 16);
    dst[0] = ((const f4v*)src)[0];
    dst[1] = ((const f4v*)src)[1];
    dst[2] = ((const f4v*)src)[2];
    dst[3] = ((const f4v*)src)[3];
    // WresL: thread t stages k=t>>3, j-chunk (t&7)*8
    const float* srw = Wres + (size_t)(k0C + (tid >> 3)) * NH + j0C + (tid & 7) * 8;
    f4v* dsw = (f4v*)(WresL + (tid >> 3) * 64 + (tid & 7) * 8);
    dsw[0] = ((const f4v*)srw)[0];
    dsw[1] = ((const f4v*)srw)[1];
  }

  // ---- INIT: hn(0)=0.01*noise[0], hnT(0), h=0, opp[0] ----
  {
    const int jg = blk & 15, bg = blk >> 4;
    if (tid < 256) {
      const int bsel = tid >> 6, jloc = tid & 63;
      const int b = bg * 4 + bsel, j = jg * 64 + jloc;
      float hv = 0.01f * noise[(size_t)b * NH + j];
      hn[(size_t)b * NH + j] = hv;
      hnT[((size_t)(j >> 1)) * 128 + b * 2 + (j & 1)] = hv;
      h[(size_t)b * NH + j] = 0.f;
      const float* wr = Wop + (size_t)j * NOPSN;
      float opo[8];
      #pragma unroll
      for (int o = 0; o < 8; ++o) opo[o] = hv * wr[o];
      #pragma unroll
      for (int off = 1; off <= 32; off <<= 1) {
        #pragma unroll
        for (int o = 0; o < 8; ++o) opo[o] += __shfl_xor(opo[o], off);
      }
      if ((tid & 63) == 0) {
        float* od = opp + (size_t)jg * 512 + (size_t)b * 8;
        #pragma unroll
        for (int o = 0; o < 8; ++o) od[o] = opo[o];
      }
    }
  }
  int ep = 0;
  gridbar(cnt, ++ep * GRID);

  for (int st = 0; st < NSTEP; ++st) {

    // ================= PHASE A =================
    // Block: x_logits[16 s][64 b], full K=1024. lane = b. Weights from LDS
    // (reloaded per step: 4x ds_read_b128), readlane broadcast; h from hnT.
    {
      smA[tid & 1023] = 0.f;                        // zero A-reduce region

      const f16v wreg = *(const f16v*)(WxL + (size_t)(kbaseA + lane) * 16);
      const float2* hb = (const float2*)hnT + ((size_t)(kbaseA >> 1)) * 64 + lane;
      float2 hA[8], hB[8];
      #pragma unroll
      for (int i = 0; i < 8; ++i) hA[i] = hb[(size_t)i * 64];
      #pragma unroll
      for (int i = 0; i < 8; ++i) hB[i] = hb[(size_t)(8 + i) * 64];

      // op-argmax for step st (blocks 0..63, wave 0) — overlaps the loads
      if (blk < NB && tid < 64) {
        const float* ob = opp + (size_t)st * 8192 + (size_t)blk * 8;
        const int o = lane & 7, jgb = lane >> 3;
        float v = ob[(size_t)jgb * 512 + o] + ob[(size_t)(jgb + 8) * 512 + o];
        v += __shfl_xor(v, 8);
        v += __shfl_xor(v, 16);
        v += __shfl_xor(v, 32);
        v += bop[o];
        float bv = bcastf(v, 0); int bo = 0;
        #pragma unroll
        for (int oo = 1; oo < 8; ++oo) {
          float vo = bcastf(v, oo);
          if (vo > bv) { bv = vo; bo = oo; }        // strict > : first-max
        }
        if (lane == 0 && bo == 0) atomicAdd(&ctrl[2 + st], 1);
      }
      __syncthreads();                              // zero visible before atomics

      f2v acc[8];
      #pragma unroll
      for (int i = 0; i < 8; ++i) acc[i] = (f2v){0.f, 0.f};

#define CHUNKA(HREG, KP0)                                                   \
      _Pragma("unroll")                                                     \
      for (int i = 0; i < 8; ++i) {                                         \
        const float2 hc = HREG[i];                                          \
        _Pragma("unroll")                                                   \
        for (int s = 0; s < 8; ++s) {                                       \
          f2v w0 = { bcastf(wreg[2*s], 2*((KP0)+i)),                        \
                     bcastf(wreg[2*s+1], 2*((KP0)+i)) };                    \
          f2v w1 = { bcastf(wreg[2*s], 2*((KP0)+i)+1),                      \
                     bcastf(wreg[2*s+1], 2*((KP0)+i)+1) };                  \
          acc[s] += w0 * hc.x;                                              \
          acc[s] += w1 * hc.y;                                              \
        }                                                                   \
      }

      CHUNKA(hA, 0)
      #pragma unroll
      for (int i = 0; i < 8; ++i) hA[i] = hb[(size_t)(16 + i) * 64];
      CHUNKA(hB, 8)
      #pragma unroll
      for (int i = 0; i < 8; ++i) hB[i] = hb[(size_t)(24 + i) * 64];
      CHUNKA(hA, 16)
      CHUNKA(hB, 24)
#undef CHUNKA

      // cross-wave K reduce via LDS atomics into [16 s][64 b] (4 KB)
      #pragma unroll
      for (int s = 0; s < 8; ++s) {
        atomicAdd(&smA[(2 * s) * 64 + lane],     acc[s].x);
        atomicAdd(&smA[(2 * s + 1) * 64 + lane], acc[s].y);
      }
      __syncthreads();
      smA[tid & 1023] += bx[s0A + ((tid & 1023) >> 6)];
      __syncthreads();
      if (tid < 64) {
        const int bb = tid;
        float bv = smA[bb]; int bs = 0;
        #pragma unroll
        for (int s2 = 1; s2 < 16; ++s2) {
          float v2 = smA[s2 * 64 + bb];
          if (v2 > bv) { bv = v2; bs = s2; }        // ascending s: first-max
        }
        float2* cp = (float2*)(wsf + OFF_CAND);
        cp[bb * 256 + blk] = make_float2(bv, __int_as_float(s0A + bs));
      }
    }
    gridbar(cnt, ++ep * GRID);

    // ================= PHASE C =================
    // Block (jgC, kgC): partial over its [128 k x 64 j] LDS weight tile for
    // all 64 b (two passes of 32). h gathered per-lane, readlane broadcast.
    {
      if (kgC >= 8) {                               // s2a half needs ptrs
        const float2* cp = (const float2*)(wsf + OFF_CAND);
        const int b0r = wv << 2;
        #pragma unroll
        for (int i = 0; i < 4; ++i) {
          const float2* row = cp + (size_t)(b0r + i) * 256;
          float2 c0 = row[lane];
          float bv = c0.x; int bi = __float_as_int(c0.y);
          #pragma unroll
          for (int q = 1; q < 4; ++q) {
            float2 c = row[q * 64 + lane];
            if (c.x > bv) { bv = c.x; bi = __float_as_int(c.y); }
          }
          #pragma unroll
          for (int off = 1; off <= 32; off <<= 1) {
            float ov = __shfl_xor(bv, off);
            int   oi = __shfl_xor(bi, off);
            if (ov > bv || (ov == bv && oi < bi)) { bv = ov; bi = oi; }
          }
          if (lane == 0) ptrSm[b0r + i] = bi;
        }
      }
      // zero the 4096-float accumulation region
      ((f4v*)smA)[tid & 1023] = (f4v){0.f, 0.f, 0.f, 0.f};
      __syncthreads();

      float wcr[8];
      #pragma unroll
      for (int i = 0; i < 8; ++i)
        wcr[i] = WresL[(size_t)((wv << 3) + i) * 64 + lane];

      const int bl = lane >> 1, half = lane & 1;
      const int ksub = k0C + (wv << 3) + (half << 2);
      const float *s0p, *s1p;
      if (kgC < 8) {
        s0p = hn + (size_t)bl * NH + ksub;
        s1p = hn + (size_t)(32 + bl) * NH + ksub;
      } else {
        int pA = ptrSm[bl], pB = ptrSm[32 + bl];
        s0p = s2a + ((size_t)bl * NS + pA) * NH + (ksub - NH);
        s1p = s2a + ((size_t)(32 + bl) * NS + pB) * NH + (ksub - NH);
      }
      f4v hr0 = *(const f4v*)s0p;
      f4v hr1 = *(const f4v*)s1p;

      {
        float acc[32];
        #pragma unroll
        for (int b = 0; b < 32; ++b) acc[b] = 0.f;
        #pragma unroll
        for (int b = 0; b < 32; ++b) {
          #pragma unroll
          for (int k = 0; k < 8; ++k)
            acc[b] += bcastf(hr0[k & 3], 2 * b + (k >> 2)) * wcr[k];
        }
        #pragma unroll
        for (int b = 0; b < 32; ++b) atomicAdd(&smA[b * 64 + lane], acc[b]);
      }
      {
        float acc[32];
        #pragma unroll
        for (int b = 0; b < 32; ++b) acc[b] = 0.f;
        #pragma unroll
        for (int b = 0; b < 32; ++b) {
          #pragma unroll
          for (int k = 0; k < 8; ++k)
            acc[b] += bcastf(hr1[k & 3], 2 * b + (k >> 2)) * wcr[k];
        }
        #pragma unroll
        for (int b = 0; b < 32; ++b) atomicAdd(&smA[2048 + b * 64 + lane], acc[b]);
      }
      __syncthreads();
      // write block's pc tile: [64 b][64 j] contiguous 16 KB
      {
        f4v v = ((const f4v*)smA)[tid & 1023];
        ((f4v*)(pc + (size_t)(kgC * 16 + jgC) * 4096))[tid & 1023] = v;
      }
    }
    gridbar(cnt, ++ep * GRID);

    // ================= PHASE D =================
    // Block (jg, bg): reduce 16 kg-partials for [4 b x 64 j], freeze logic,
    // next h_n + opp epilogue (R5-verified; scratch moved to smA).
    {
      const int jg = blk & 15, bg = blk >> 4;
      const int j0 = jg << 6, b0 = bg << 2;
      const int q = tid >> 8, idx = tid & 255;
      {
        const int bsel = idx >> 6, jloc = idx & 63;
        float s = 0.f;
        #pragma unroll
        for (int kk = 0; kk < 4; ++kk) {
          const int kg = q * 4 + kk;
          s += pc[((size_t)(kg * 16 + jg) * 64 + (b0 + bsel)) * 64 + jloc];
        }
        smA[q * 256 + idx] = s;
      }
      __syncthreads();

      if (tid < 256) {
        const int bsel = tid >> 6, jloc = tid & 63;
        float v = bres[j0 + jloc] + smA[tid] + smA[256 + tid]
                + smA[512 + tid] + smA[768 + tid];
        int done = 0;
        for (int tt = 0; tt < st; ++tt) done |= (ctrl[2 + tt] == NB) ? 1 : 0;
        const int b = b0 + bsel, j = j0 + jloc;
        float hold = h[(size_t)b * NH + j];
        float hout = done ? hold : v;
        h[(size_t)b * NH + j] = hout;
        if (st < NSTEP - 1) {
          float hnv = hout + 0.01f * noise[(size_t)(st + 1) * (NB * NH) + (size_t)b * NH + j];
          hn[(size_t)b * NH + j] = hnv;
          hnT[((size_t)(j >> 1)) * 128 + b * 2 + (j & 1)] = hnv;
          const float* wr = Wop + (size_t)j * NOPSN;
          float opo[8];
          #pragma unroll
          for (int o = 0; o < 8; ++o) opo[o] = hnv * wr[o];
          #pragma unroll
          for (int off = 1; off <= 32; off <<= 1) {
            #pragma unroll
            for (int o = 0; o < 8; ++o) opo[o] += __shfl_xor(opo[o], off);
          }
          if ((tid & 63) == 0) {
            float* od = opp + ((size_t)(st + 1) * 16 + jg) * 512 + (size_t)b * 8;
            #pragma unroll
            for (int o = 0; o < 8; ++o) od[o] = opo[o];
          }
        } else {
          out[(size_t)b * NH + j] = hout;
        }
      }
    }
    if (st < NSTEP - 1) gridbar(cnt, ++ep * GRID);
  }
}

extern "C" void kernel_launch(void* const* d_in, const int* in_sizes, int n_in,
                              void* d_out, int out_size, void* d_ws, size_t ws_size,
                              hipStream_t stream) {
  const float* s2a   = (const float*)d_in[0];
  const float* Wres  = (const float*)d_in[1];
  const float* bres  = (const float*)d_in[2];
  const float* Wop   = (const float*)d_in[3];
  const float* bop   = (const float*)d_in[4];
  const float* Wx    = (const float*)d_in[5];
  const float* bx    = (const float*)d_in[6];
  const float* noise = (const float*)d_in[7];
  float* outp = (float*)d_out;
  float* wsf  = (float*)d_ws;   // needs ~5.5 MB
  hipLaunchKernelGGL(sys1_kernel, dim3(GRID), dim3(TPB), 0, stream,
                     s2a, Wres, bres, Wop, bop, Wx, bx, noise, outp, wsf);
}

// Round 7
// 2779.336 us; speedup vs baseline: 1.0753x; 1.0753x over previous
//
#include <hip/hip_runtime.h>
#include <cstdint>
#include <cstddef>

// Problem constants
#define NB    64      // batch
#define NS    4096    // seq len
#define NH    1024    // hidden
#define NOPSN 8
#define NSTEP 10

#define GRID  256
#define TPB   1024    // 16 waves/block, 1 block/CU -> 4 waves/SIMD

// Workspace layout (float offsets), ~1.8 MB (R3-verified).
// hn/hnT double-buffered by step parity; hnT = k-pair interleave:
// element (k,b) at [(k>>1)*128 + b*2 + (k&1)]
#define OFF_HN0  0u
#define OFF_HN1  65536u
#define OFF_HT0  131072u
#define OFF_HT1  196608u
#define OFF_H    262144u
#define OFF_CAND 327680u   // cand [64][256] float2 (val, idx-as-float)
#define OFF_OPP  360448u   // opp [10][16 jg][64 b][8 o]
#define OFF_CTRL 442368u   // ints: [0]=magic [1]=barrier cnt [2..11]=stopcnt[t]
#define MAGIC    0x1357A5E5

typedef float f2v  __attribute__((ext_vector_type(2)));
typedef float f4v  __attribute__((ext_vector_type(4)));
typedef float f16v __attribute__((ext_vector_type(16)));

__device__ __forceinline__ float bcastf(float v, int l) {
  return __int_as_float(__builtin_amdgcn_readlane(__float_as_int(v), l));
}

// Device-scope grid barrier with full fences (R3-verified).
__device__ __forceinline__ void gridbar(int* cnt, int target) {
  __syncthreads();
  if (threadIdx.x == 0) {
    __threadfence();  // release (device scope)
    __hip_atomic_fetch_add(cnt, 1, __ATOMIC_RELAXED, __HIP_MEMORY_SCOPE_AGENT);
    while (__hip_atomic_load(cnt, __ATOMIC_RELAXED, __HIP_MEMORY_SCOPE_AGENT) < target)
      __builtin_amdgcn_s_sleep(1);
    __threadfence();  // acquire
  }
  __syncthreads();
}

__global__ void __launch_bounds__(TPB, 4)
sys1_kernel(const float* __restrict__ s2a,  const float* __restrict__ Wres,
            const float* __restrict__ bres, const float* __restrict__ Wop,
            const float* __restrict__ bop,  const float* __restrict__ Wx,
            const float* __restrict__ bx,   const float* __restrict__ noise,
            float* __restrict__ out,        float* __restrict__ wsf)
{
  __shared__ float smem[16384];   // 64 KB: cross-wave reductions only

  float* __restrict__ h   = wsf + OFF_H;
  float* __restrict__ opp = wsf + OFF_OPP;
  int* ctrl = (int*)(wsf + OFF_CTRL);
  int* cnt  = ctrl + 1;

  const int tid = threadIdx.x;
  const int blk = blockIdx.x;

  // ---- bootstrap: block 0 inits ctrl (ws is poisoned every launch) ----
  if (blk == 0 && tid == 0) {
    #pragma unroll
    for (int i = 1; i < 32; ++i) ctrl[i] = 0;
    __threadfence();
    __hip_atomic_store(&ctrl[0], (int)MAGIC, __ATOMIC_RELEASE, __HIP_MEMORY_SCOPE_AGENT);
  }
  if (tid == 0) {
    while (__hip_atomic_load(&ctrl[0], __ATOMIC_RELAXED, __HIP_MEMORY_SCOPE_AGENT) != (int)MAGIC)
      __builtin_amdgcn_s_sleep(1);
  }
  __syncthreads();

  const int lane = tid & 63;
  const int wv   = __builtin_amdgcn_readfirstlane(tid >> 6);   // wave 0..15

  // ---- phase-A weights: ONE per-lane 64B load, pinned in 16 VGPRs ----
  const int s0A = blk << 4;
  const int kbaseA = wv << 6;
  float wr[16];
  {
    f16v wv0 = *(const f16v*)(Wx + (size_t)(kbaseA + lane) * NS + s0A);
    #pragma unroll
    for (int i = 0; i < 16; ++i) wr[i] = wv0[i];
  }

  // phase-C block mapping: XCD-aware (blk%8 assumed XCD) so the 16 blocks
  // sharing a jg land on one XCD -> Wres fetched once per XCD.
  const int jgC = ((blk & 7) << 1) | ((blk >> 3) & 1);
  const int bgC = blk >> 4;

  // ---- INIT: hn(0)=0.01*noise[0] into parity-0, h=0, opp[0] ----
  {
    const int jg = blk & 15, bg = blk >> 4;
    if (tid < 256) {
      const int bsel = tid >> 6, jloc = tid & 63;
      const int b = bg * 4 + bsel, j = jg * 64 + jloc;
      float hv = 0.01f * noise[(size_t)b * NH + j];
      (wsf + OFF_HN0)[(size_t)b * NH + j] = hv;
      (wsf + OFF_HT0)[((size_t)(j >> 1)) * 128 + b * 2 + (j & 1)] = hv;
      h[(size_t)b * NH + j] = 0.f;
      const float* wrp = Wop + (size_t)j * NOPSN;
      float opo[8];
      #pragma unroll
      for (int o = 0; o < 8; ++o) opo[o] = hv * wrp[o];
      #pragma unroll
      for (int off = 1; off <= 32; off <<= 1) {
        #pragma unroll
        for (int o = 0; o < 8; ++o) opo[o] += __shfl_xor(opo[o], off);
      }
      if ((tid & 63) == 0) {
        float* od = opp + (size_t)jg * 512 + (size_t)b * 8;
        #pragma unroll
        for (int o = 0; o < 8; ++o) od[o] = opo[o];
      }
    }
  }
  int ep = 0;
  gridbar(cnt, ++ep * GRID);

  for (int st = 0; st < NSTEP; ++st) {
    // pin wr[] live across the loop -> compiler cannot remat the Wx load
    #pragma unroll
    for (int i = 0; i < 16; ++i) asm volatile("" : "+v"(wr[i]));

    const float* __restrict__ hn_cur  = wsf + ((st & 1) ? OFF_HN1 : OFF_HN0);
    float* __restrict__       hn_nxt  = wsf + ((st & 1) ? OFF_HN0 : OFF_HN1);
    const float* __restrict__ hnT_cur = wsf + ((st & 1) ? OFF_HT1 : OFF_HT0);
    float* __restrict__       hnT_nxt = wsf + ((st & 1) ? OFF_HT0 : OFF_HT1);

    // ================= PHASE A =================
    // Block: x_logits[16 s][64 b], full K=1024. lane = b. Weights in pinned
    // VGPRs (zero fetch); h from hnT (per-lane float2), readlane broadcast.
    {
      const float2* hb = (const float2*)hnT_cur + ((size_t)(kbaseA >> 1)) * 64 + lane;
      float2 hA[8], hB[8];
      #pragma unroll
      for (int i = 0; i < 8; ++i) hA[i] = hb[(size_t)i * 64];
      #pragma unroll
      for (int i = 0; i < 8; ++i) hB[i] = hb[(size_t)(8 + i) * 64];

      // op-argmax for step st (blocks 0..63, wave 0) — overlaps the loads
      if (blk < NB && tid < 64) {
        const float* ob = opp + (size_t)st * 8192 + (size_t)blk * 8;
        const int o = lane & 7, jgb = lane >> 3;
        float v = ob[(size_t)jgb * 512 + o] + ob[(size_t)(jgb + 8) * 512 + o];
        v += __shfl_xor(v, 8);
        v += __shfl_xor(v, 16);
        v += __shfl_xor(v, 32);
        v += bop[o];
        float bv = bcastf(v, 0); int bo = 0;
        #pragma unroll
        for (int oo = 1; oo < 8; ++oo) {
          float vo = bcastf(v, oo);
          if (vo > bv) { bv = vo; bo = oo; }        // strict > : first-max
        }
        if (lane == 0 && bo == 0) atomicAdd(&ctrl[2 + st], 1);
      }

      f2v acc[8];
      #pragma unroll
      for (int i = 0; i < 8; ++i) acc[i] = (f2v){0.f, 0.f};

#define CHUNKA(HREG, KP0)                                                   \
      _Pragma("unroll")                                                     \
      for (int i = 0; i < 8; ++i) {                                         \
        const float2 hc = HREG[i];                                          \
        _Pragma("unroll")                                                   \
        for (int s = 0; s < 8; ++s) {                                       \
          f2v w0 = { bcastf(wr[2*s], 2*((KP0)+i)),                          \
                     bcastf(wr[2*s+1], 2*((KP0)+i)) };                      \
          f2v w1 = { bcastf(wr[2*s], 2*((KP0)+i)+1),                        \
                     bcastf(wr[2*s+1], 2*((KP0)+i)+1) };                    \
          acc[s] += w0 * hc.x;                                              \
          acc[s] += w1 * hc.y;                                              \
        }                                                                   \
      }

      CHUNKA(hA, 0)
      #pragma unroll
      for (int i = 0; i < 8; ++i) hA[i] = hb[(size_t)(16 + i) * 64];
      CHUNKA(hB, 8)
      #pragma unroll
      for (int i = 0; i < 8; ++i) hB[i] = hb[(size_t)(24 + i) * 64];
      CHUNKA(hA, 16)
      CHUNKA(hB, 24)
#undef CHUNKA

      // cross-wave K reduction: red[16 w][16 s][64 b]
      #pragma unroll
      for (int s = 0; s < 8; ++s) {
        smem[wv * 1024 + (2 * s) * 64 + lane]     = acc[s].x;
        smem[wv * 1024 + (2 * s + 1) * 64 + lane] = acc[s].y;
      }
      __syncthreads();
      {
        const int s = tid >> 6, b = tid & 63;
        float val = bx[s0A + s];
        #pragma unroll
        for (int w = 0; w < 16; ++w) val += smem[w * 1024 + s * 64 + b];
        __syncthreads();
        smem[s * 64 + b] = val;
        __syncthreads();
        if (tid < 64) {
          const int bb = tid;
          float bv = smem[bb]; int bs = 0;
          #pragma unroll
          for (int s2 = 1; s2 < 16; ++s2) {
            float v2 = smem[s2 * 64 + bb];
            if (v2 > bv) { bv = v2; bs = s2; }      // ascending s: first-max
          }
          float2* cp = (float2*)(wsf + OFF_CAND);
          cp[bb * 256 + blk] = make_float2(bv, __int_as_float(s0A + bs));
        }
      }
    }
    gridbar(cnt, ++ep * GRID);

    // ================= PHASE C =================
    // Block (jgC: 64 j, bgC: 4 b): h_new full K=2048. lane = j (per-lane
    // coalesced weights, 16-deep double-buffered prefetch); h/s2a via
    // wave-uniform f4v loads. Epilogue fused (freeze, noise, opp).
    {
      const int j0 = jgC << 6, b0 = bgC << 2;

      int ptrs[4] = {0, 0, 0, 0};
      if (wv >= 8) {                                 // only s2a half needs ptrs
        const float2* cp = (const float2*)(wsf + OFF_CAND);
        #pragma unroll
        for (int i = 0; i < 4; ++i) {
          const float2* row = cp + (size_t)(b0 + i) * 256;
          float2 c0 = row[lane];
          float bv = c0.x; int bi = __float_as_int(c0.y);
          #pragma unroll
          for (int q = 1; q < 4; ++q) {
            float2 c = row[q * 64 + lane];
            if (c.x > bv) { bv = c.x; bi = __float_as_int(c.y); }
          }
          #pragma unroll
          for (int off = 1; off <= 32; off <<= 1) {
            float ov = __shfl_xor(bv, off);
            int   oi = __shfl_xor(bi, off);
            if (ov > bv || (ov == bv && oi < bi)) { bv = ov; bi = oi; }
          }
          ptrs[i] = __builtin_amdgcn_readfirstlane(bi);
        }
      }
      int done = 0;
      for (int tt = 0; tt < st; ++tt) done |= (ctrl[2 + tt] == NB) ? 1 : 0;

      const int kb = wv << 7;                        // 128 k per wave
      const float *p0, *p1, *p2, *p3;                // wave-uniform bases
      if (wv < 8) {
        p0 = hn_cur + (size_t)(b0 + 0) * NH + kb;
        p1 = hn_cur + (size_t)(b0 + 1) * NH + kb;
        p2 = hn_cur + (size_t)(b0 + 2) * NH + kb;
        p3 = hn_cur + (size_t)(b0 + 3) * NH + kb;
      } else {
        p0 = s2a + ((size_t)(b0 + 0) * NS + ptrs[0]) * NH + (kb - NH);
        p1 = s2a + ((size_t)(b0 + 1) * NS + ptrs[1]) * NH + (kb - NH);
        p2 = s2a + ((size_t)(b0 + 2) * NS + ptrs[2]) * NH + (kb - NH);
        p3 = s2a + ((size_t)(b0 + 3) * NS + ptrs[3]) * NH + (kb - NH);
      }
      const float* wp = Wres + (size_t)kb * NH + j0 + lane;   // per-lane

      float a0 = 0.f, a1 = 0.f, a2 = 0.f, a3 = 0.f;
      float wcur[16], wnxt[16];
      #pragma unroll
      for (int i = 0; i < 16; ++i) wcur[i] = wp[(size_t)i * NH];

      #pragma unroll
      for (int c = 0; c < 8; ++c) {
        const int K0 = c * 16;
        if (c < 7) {
          #pragma unroll
          for (int i = 0; i < 16; ++i) wnxt[i] = wp[(size_t)(K0 + 16 + i) * NH];
        }
        f4v q0[4], q1[4], q2[4], q3[4];
        #pragma unroll
        for (int i = 0; i < 4; ++i) {
          q0[i] = *(const f4v*)(p0 + K0 + 4 * i);
          q1[i] = *(const f4v*)(p1 + K0 + 4 * i);
          q2[i] = *(const f4v*)(p2 + K0 + 4 * i);
          q3[i] = *(const f4v*)(p3 + K0 + 4 * i);
        }
        #pragma unroll
        for (int i = 0; i < 16; ++i) {
          const float w = wcur[i];
          a0 += q0[i >> 2][i & 3] * w;
          a1 += q1[i >> 2][i & 3] * w;
          a2 += q2[i >> 2][i & 3] * w;
          a3 += q3[i >> 2][i & 3] * w;
        }
        if (c < 7) {
          #pragma unroll
          for (int i = 0; i < 16; ++i) wcur[i] = wnxt[i];
        }
      }

      // cross-wave reduce: red[16 w][4 b][64 j]
      smem[wv * 256 + 0 * 64 + lane] = a0;
      smem[wv * 256 + 1 * 64 + lane] = a1;
      smem[wv * 256 + 2 * 64 + lane] = a2;
      smem[wv * 256 + 3 * 64 + lane] = a3;
      __syncthreads();

      if (tid < 256) {
        const int bsel = tid >> 6, jloc = tid & 63;
        float v = bres[j0 + jloc];
        #pragma unroll
        for (int w = 0; w < 16; ++w) v += smem[w * 256 + bsel * 64 + jloc];
        const int b = b0 + bsel, j = j0 + jloc;
        float hold = h[(size_t)b * NH + j];
        float hout = done ? hold : v;
        h[(size_t)b * NH + j] = hout;
        if (st < NSTEP - 1) {
          float hnv = hout + 0.01f * noise[(size_t)(st + 1) * (NB * NH) + (size_t)b * NH + j];
          hn_nxt[(size_t)b * NH + j] = hnv;
          hnT_nxt[((size_t)(j >> 1)) * 128 + b * 2 + (j & 1)] = hnv;
          const float* wrp = Wop + (size_t)j * NOPSN;
          float opo[8];
          #pragma unroll
          for (int o = 0; o < 8; ++o) opo[o] = hnv * wrp[o];
          #pragma unroll
          for (int off = 1; off <= 32; off <<= 1) {
            #pragma unroll
            for (int o = 0; o < 8; ++o) opo[o] += __shfl_xor(opo[o], off);
          }
          if ((tid & 63) == 0) {
            float* od = opp + ((size_t)(st + 1) * 16 + jgC) * 512 + (size_t)b * 8;
            #pragma unroll
            for (int o = 0; o < 8; ++o) od[o] = opo[o];
          }
        } else {
          out[(size_t)b * NH + j] = hout;
        }
      }
    }
    if (st < NSTEP - 1) gridbar(cnt, ++ep * GRID);
  }
}

extern "C" void kernel_launch(void* const* d_in, const int* in_sizes, int n_in,
                              void* d_out, int out_size, void* d_ws, size_t ws_size,
                              hipStream_t stream) {
  const float* s2a   = (const float*)d_in[0];
  const float* Wres  = (const float*)d_in[1];
  const float* bres  = (const float*)d_in[2];
  const float* Wop   = (const float*)d_in[3];
  const float* bop   = (const float*)d_in[4];
  const float* Wx    = (const float*)d_in[5];
  const float* bx    = (const float*)d_in[6];
  const float* noise = (const float*)d_in[7];
  float* outp = (float*)d_out;
  float* wsf  = (float*)d_ws;   // needs ~1.8 MB
  hipLaunchKernelGGL(sys1_kernel, dim3(GRID), dim3(TPB), 0, stream,
                     s2a, Wres, bres, Wop, bop, Wx, bx, noise, outp, wsf);
}

// Round 8
// 2224.642 us; speedup vs baseline: 1.3434x; 1.2493x over previous
//
#include <hip/hip_runtime.h>
#include <cstdint>
#include <cstddef>

// Problem constants
#define NB    64      // batch
#define NS    4096    // seq len
#define NH    1024    // hidden
#define NOPSN 8
#define NSTEP 10

#define GRID  256
#define TPB   1024    // 16 waves/block, 1 block/CU -> 4 waves/SIMD

// Workspace layout (float offsets), ~1.8 MB (R3-verified).
// hn/hnT double-buffered by step parity; hnT = k-pair interleave:
// element (k,b) at [(k>>1)*128 + b*2 + (k&1)]
#define OFF_HN0  0u
#define OFF_HN1  65536u
#define OFF_HT0  131072u
#define OFF_HT1  196608u
#define OFF_H    262144u
#define OFF_CAND 327680u   // cand [64][256] float2 (val, idx-as-float)
#define OFF_OPP  360448u   // opp [10][16 jg][64 b][8 o]
#define OFF_CTRL 442368u   // ints: [0]=magic [1]=barrier cnt [2..11]=stopcnt[t]
#define MAGIC    0x1357A5E5

typedef float f2v  __attribute__((ext_vector_type(2)));
typedef float f4v  __attribute__((ext_vector_type(4)));
typedef float f16v __attribute__((ext_vector_type(16)));

__device__ __forceinline__ float bcastf(float v, int l) {
  return __int_as_float(__builtin_amdgcn_readlane(__float_as_int(v), l));
}

// Device-scope grid barrier with full fences (R3-verified).
__device__ __forceinline__ void gridbar(int* cnt, int target) {
  __syncthreads();
  if (threadIdx.x == 0) {
    __threadfence();  // release (device scope)
    __hip_atomic_fetch_add(cnt, 1, __ATOMIC_RELAXED, __HIP_MEMORY_SCOPE_AGENT);
    while (__hip_atomic_load(cnt, __ATOMIC_RELAXED, __HIP_MEMORY_SCOPE_AGENT) < target)
      __builtin_amdgcn_s_sleep(1);
    __threadfence();  // acquire
  }
  __syncthreads();
}

// waves_per_eu(4,4): real occupancy is exactly 4 waves/EU (16 waves/block,
// 1 block/CU) -> tell the allocator so it uses the full 128-VGPR budget
// instead of squeezing to 64 and spilling (R7) / collapsing pipelines (R3).
__global__ void __launch_bounds__(TPB)
__attribute__((amdgpu_waves_per_eu(4, 4)))
sys1_kernel(const float* __restrict__ s2a,  const float* __restrict__ Wres,
            const float* __restrict__ bres, const float* __restrict__ Wop,
            const float* __restrict__ bop,  const float* __restrict__ Wx,
            const float* __restrict__ bx,   const float* __restrict__ noise,
            float* __restrict__ out,        float* __restrict__ wsf)
{
  __shared__ float smem[16384];   // 64 KB: cross-wave reductions only

  float* __restrict__ h   = wsf + OFF_H;
  float* __restrict__ opp = wsf + OFF_OPP;
  int* ctrl = (int*)(wsf + OFF_CTRL);
  int* cnt  = ctrl + 1;

  const int tid = threadIdx.x;
  const int blk = blockIdx.x;

  // ---- bootstrap: block 0 inits ctrl (ws is poisoned every launch) ----
  if (blk == 0 && tid == 0) {
    #pragma unroll
    for (int i = 1; i < 32; ++i) ctrl[i] = 0;
    __threadfence();
    __hip_atomic_store(&ctrl[0], (int)MAGIC, __ATOMIC_RELEASE, __HIP_MEMORY_SCOPE_AGENT);
  }
  if (tid == 0) {
    while (__hip_atomic_load(&ctrl[0], __ATOMIC_RELAXED, __HIP_MEMORY_SCOPE_AGENT) != (int)MAGIC)
      __builtin_amdgcn_s_sleep(1);
  }
  __syncthreads();

  const int lane = tid & 63;
  const int wv   = __builtin_amdgcn_readfirstlane(tid >> 6);   // wave 0..15

  const int s0A = blk << 4;            // phase-A s-cols
  const int kbaseA = wv << 6;          // phase-A wave k-slice

  // ---- INIT: hn(0)=0.01*noise[0] into parity-0, h=0, opp[0] ----
  {
    const int jg = blk & 15, bg = blk >> 4;
    if (tid < 256) {
      const int bsel = tid >> 6, jloc = tid & 63;
      const int b = bg * 4 + bsel, j = jg * 64 + jloc;
      float hv = 0.01f * noise[(size_t)b * NH + j];
      (wsf + OFF_HN0)[(size_t)b * NH + j] = hv;
      (wsf + OFF_HT0)[((size_t)(j >> 1)) * 128 + b * 2 + (j & 1)] = hv;
      h[(size_t)b * NH + j] = 0.f;
      const float* wrp = Wop + (size_t)j * NOPSN;
      float opo[8];
      #pragma unroll
      for (int o = 0; o < 8; ++o) opo[o] = hv * wrp[o];
      #pragma unroll
      for (int off = 1; off <= 32; off <<= 1) {
        #pragma unroll
        for (int o = 0; o < 8; ++o) opo[o] += __shfl_xor(opo[o], off);
      }
      if ((tid & 63) == 0) {
        float* od = opp + (size_t)jg * 512 + (size_t)b * 8;
        #pragma unroll
        for (int o = 0; o < 8; ++o) od[o] = opo[o];
      }
    }
  }
  int ep = 0;
  gridbar(cnt, ++ep * GRID);

  for (int st = 0; st < NSTEP; ++st) {
    const float* __restrict__ hn_cur  = wsf + ((st & 1) ? OFF_HN1 : OFF_HN0);
    float* __restrict__       hn_nxt  = wsf + ((st & 1) ? OFF_HN0 : OFF_HN1);
    const float* __restrict__ hnT_cur = wsf + ((st & 1) ? OFF_HT1 : OFF_HT0);
    float* __restrict__       hnT_nxt = wsf + ((st & 1) ? OFF_HT0 : OFF_HT1);

    // ================= PHASE A =================
    // Block: x_logits[16 s][64 b], full K=1024. lane = b.
    // Weights: ONE per-lane 64B f16v load (whole wave slice in parallel).
    // h: ALL 32 float2 loads issued up front -> single latency exposure,
    // then 2048 VALU ops with zero memory stalls (readlane broadcast).
    {
      const f16v wreg = *(const f16v*)(Wx + (size_t)(kbaseA + lane) * NS + s0A);
      const float2* hb = (const float2*)hnT_cur + ((size_t)(kbaseA >> 1)) * 64 + lane;
      float2 hh[32];
      #pragma unroll
      for (int i = 0; i < 32; ++i) hh[i] = hb[(size_t)i * 64];

      // op-argmax for step st (blocks 0..63, wave 0) — overlaps the loads
      if (blk < NB && tid < 64) {
        const float* ob = opp + (size_t)st * 8192 + (size_t)blk * 8;
        const int o = lane & 7, jgb = lane >> 3;
        float v = ob[(size_t)jgb * 512 + o] + ob[(size_t)(jgb + 8) * 512 + o];
        v += __shfl_xor(v, 8);
        v += __shfl_xor(v, 16);
        v += __shfl_xor(v, 32);
        v += bop[o];
        float bv = bcastf(v, 0); int bo = 0;
        #pragma unroll
        for (int oo = 1; oo < 8; ++oo) {
          float vo = bcastf(v, oo);
          if (vo > bv) { bv = vo; bo = oo; }        // strict > : first-max
        }
        if (lane == 0 && bo == 0) atomicAdd(&ctrl[2 + st], 1);
      }

      f2v acc[8];
      #pragma unroll
      for (int i = 0; i < 8; ++i) acc[i] = (f2v){0.f, 0.f};

      #pragma unroll
      for (int kp = 0; kp < 32; ++kp) {
        const float2 hc = hh[kp];
        #pragma unroll
        for (int s = 0; s < 8; ++s) {
          f2v w0 = { bcastf(wreg[2 * s],     2 * kp),
                     bcastf(wreg[2 * s + 1], 2 * kp) };
          f2v w1 = { bcastf(wreg[2 * s],     2 * kp + 1),
                     bcastf(wreg[2 * s + 1], 2 * kp + 1) };
          acc[s] += w0 * hc.x;
          acc[s] += w1 * hc.y;
        }
      }

      // cross-wave K reduction: red[16 w][16 s][64 b]
      #pragma unroll
      for (int s = 0; s < 8; ++s) {
        smem[wv * 1024 + (2 * s) * 64 + lane]     = acc[s].x;
        smem[wv * 1024 + (2 * s + 1) * 64 + lane] = acc[s].y;
      }
      __syncthreads();
      {
        const int s = tid >> 6, b = tid & 63;
        float val = bx[s0A + s];
        #pragma unroll
        for (int w = 0; w < 16; ++w) val += smem[w * 1024 + s * 64 + b];
        __syncthreads();
        smem[s * 64 + b] = val;
        __syncthreads();
        if (tid < 64) {
          const int bb = tid;
          float bv = smem[bb]; int bs = 0;
          #pragma unroll
          for (int s2 = 1; s2 < 16; ++s2) {
            float v2 = smem[s2 * 64 + bb];
            if (v2 > bv) { bv = v2; bs = s2; }      // ascending s: first-max
          }
          float2* cp = (float2*)(wsf + OFF_CAND);
          cp[bb * 256 + blk] = make_float2(bv, __int_as_float(s0A + bs));
        }
      }
    }
    gridbar(cnt, ++ep * GRID);

    // ================= PHASE C =================
    // Block (jg: 64 j, bg: 4 b): h_new full K=2048. lane = j (per-lane
    // coalesced weights), h/s2a wave-uniform f4v loads. 8-k chunks,
    // double-buffered (16 loads in flight/chunk; live set ~96 VGPR).
    {
      const int jg = blk & 15, bg = blk >> 4;
      const int j0 = jg << 6, b0 = bg << 2;

      int ptrs[4] = {0, 0, 0, 0};
      if (wv >= 8) {                                 // only s2a half needs ptrs
        const float2* cp = (const float2*)(wsf + OFF_CAND);
        #pragma unroll
        for (int i = 0; i < 4; ++i) {
          const float2* row = cp + (size_t)(b0 + i) * 256;
          float2 c0 = row[lane];
          float bv = c0.x; int bi = __float_as_int(c0.y);
          #pragma unroll
          for (int q = 1; q < 4; ++q) {
            float2 c = row[q * 64 + lane];
            if (c.x > bv) { bv = c.x; bi = __float_as_int(c.y); }
          }
          #pragma unroll
          for (int off = 1; off <= 32; off <<= 1) {
            float ov = __shfl_xor(bv, off);
            int   oi = __shfl_xor(bi, off);
            if (ov > bv || (ov == bv && oi < bi)) { bv = ov; bi = oi; }
          }
          ptrs[i] = __builtin_amdgcn_readfirstlane(bi);
        }
      }
      int done = 0;
      for (int tt = 0; tt < st; ++tt) done |= (ctrl[2 + tt] == NB) ? 1 : 0;

      const int kb = wv << 7;                        // 128 k per wave
      const float *p0, *p1, *p2, *p3;                // wave-uniform bases
      if (wv < 8) {
        p0 = hn_cur + (size_t)(b0 + 0) * NH + kb;
        p1 = hn_cur + (size_t)(b0 + 1) * NH + kb;
        p2 = hn_cur + (size_t)(b0 + 2) * NH + kb;
        p3 = hn_cur + (size_t)(b0 + 3) * NH + kb;
      } else {
        p0 = s2a + ((size_t)(b0 + 0) * NS + ptrs[0]) * NH + (kb - NH);
        p1 = s2a + ((size_t)(b0 + 1) * NS + ptrs[1]) * NH + (kb - NH);
        p2 = s2a + ((size_t)(b0 + 2) * NS + ptrs[2]) * NH + (kb - NH);
        p3 = s2a + ((size_t)(b0 + 3) * NS + ptrs[3]) * NH + (kb - NH);
      }
      const float* wp = Wres + (size_t)kb * NH + j0 + lane;   // per-lane

      float a0 = 0.f, a1 = 0.f, a2 = 0.f, a3 = 0.f;
      float wA[8], wB[8];
      f4v   qA[8], qB[8];     // [b*2 + half]

      #pragma unroll
      for (int i = 0; i < 8; ++i) wA[i] = wp[(size_t)i * NH];
      #pragma unroll
      for (int i = 0; i < 2; ++i) {
        qA[0 + i] = *(const f4v*)(p0 + 4 * i);
        qA[2 + i] = *(const f4v*)(p1 + 4 * i);
        qA[4 + i] = *(const f4v*)(p2 + 4 * i);
        qA[6 + i] = *(const f4v*)(p3 + 4 * i);
      }

#define CSTEP(CUR, NXT, C)                                                  \
      {                                                                     \
        if ((C) < 15) {                                                     \
          _Pragma("unroll")                                                 \
          for (int i = 0; i < 8; ++i)                                       \
            w##NXT[i] = wp[(size_t)(((C) + 1) * 8 + i) * NH];               \
          _Pragma("unroll")                                                 \
          for (int i = 0; i < 2; ++i) {                                     \
            q##NXT[0 + i] = *(const f4v*)(p0 + ((C) + 1) * 8 + 4 * i);      \
            q##NXT[2 + i] = *(const f4v*)(p1 + ((C) + 1) * 8 + 4 * i);      \
            q##NXT[4 + i] = *(const f4v*)(p2 + ((C) + 1) * 8 + 4 * i);      \
            q##NXT[6 + i] = *(const f4v*)(p3 + ((C) + 1) * 8 + 4 * i);      \
          }                                                                 \
        }                                                                   \
        _Pragma("unroll")                                                   \
        for (int i = 0; i < 8; ++i) {                                       \
          const float w = w##CUR[i];                                        \
          a0 += q##CUR[0 + (i >> 2)][i & 3] * w;                            \
          a1 += q##CUR[2 + (i >> 2)][i & 3] * w;                            \
          a2 += q##CUR[4 + (i >> 2)][i & 3] * w;                            \
          a3 += q##CUR[6 + (i >> 2)][i & 3] * w;                            \
        }                                                                   \
      }

      CSTEP(A, B, 0)  CSTEP(B, A, 1)  CSTEP(A, B, 2)  CSTEP(B, A, 3)
      CSTEP(A, B, 4)  CSTEP(B, A, 5)  CSTEP(A, B, 6)  CSTEP(B, A, 7)
      CSTEP(A, B, 8)  CSTEP(B, A, 9)  CSTEP(A, B, 10) CSTEP(B, A, 11)
      CSTEP(A, B, 12) CSTEP(B, A, 13) CSTEP(A, B, 14) CSTEP(B, A, 15)
#undef CSTEP

      // cross-wave reduce: red[16 w][4 b][64 j]
      smem[wv * 256 + 0 * 64 + lane] = a0;
      smem[wv * 256 + 1 * 64 + lane] = a1;
      smem[wv * 256 + 2 * 64 + lane] = a2;
      smem[wv * 256 + 3 * 64 + lane] = a3;
      __syncthreads();

      if (tid < 256) {
        const int bsel = tid >> 6, jloc = tid & 63;
        float v = bres[j0 + jloc];
        #pragma unroll
        for (int w = 0; w < 16; ++w) v += smem[w * 256 + bsel * 64 + jloc];
        const int b = b0 + bsel, j = j0 + jloc;
        float hold = h[(size_t)b * NH + j];
        float hout = done ? hold : v;
        h[(size_t)b * NH + j] = hout;
        if (st < NSTEP - 1) {
          float hnv = hout + 0.01f * noise[(size_t)(st + 1) * (NB * NH) + (size_t)b * NH + j];
          hn_nxt[(size_t)b * NH + j] = hnv;
          hnT_nxt[((size_t)(j >> 1)) * 128 + b * 2 + (j & 1)] = hnv;
          const float* wrp = Wop + (size_t)j * NOPSN;
          float opo[8];
          #pragma unroll
          for (int o = 0; o < 8; ++o) opo[o] = hnv * wrp[o];
          #pragma unroll
          for (int off = 1; off <= 32; off <<= 1) {
            #pragma unroll
            for (int o = 0; o < 8; ++o) opo[o] += __shfl_xor(opo[o], off);
          }
          if ((tid & 63) == 0) {
            float* od = opp + ((size_t)(st + 1) * 16 + jg) * 512 + (size_t)b * 8;
            #pragma unroll
            for (int o = 0; o < 8; ++o) od[o] = opo[o];
          }
        } else {
          out[(size_t)b * NH + j] = hout;
        }
      }
    }
    if (st < NSTEP - 1) gridbar(cnt, ++ep * GRID);
  }
}

extern "C" void kernel_launch(void* const* d_in, const int* in_sizes, int n_in,
                              void* d_out, int out_size, void* d_ws, size_t ws_size,
                              hipStream_t stream) {
  const float* s2a   = (const float*)d_in[0];
  const float* Wres  = (const float*)d_in[1];
  const float* bres  = (const float*)d_in[2];
  const float* Wop   = (const float*)d_in[3];
  const float* bop   = (const float*)d_in[4];
  const float* Wx    = (const float*)d_in[5];
  const float* bx    = (const float*)d_in[6];
  const float* noise = (const float*)d_in[7];
  float* outp = (float*)d_out;
  float* wsf  = (float*)d_ws;   // needs ~1.8 MB
  hipLaunchKernelGGL(sys1_kernel, dim3(GRID), dim3(TPB), 0, stream,
                     s2a, Wres, bres, Wop, bop, Wx, bx, noise, outp, wsf);
}